// Round 5
// baseline (350.094 us; speedup 1.0000x reference)
//
#include <hip/hip_runtime.h>
#include <hip/hip_cooperative_groups.h>
#include <hip/hip_fp16.h>
#include <math.h>

namespace cg = cooperative_groups;

#define N_NODES 100000
#define N_EDGES 3200000
#define D_IN    128
#define H1      16

#define PSH     8                      // packing shift: (src<<8 | dloc), dloc < 256
#define NPB     200                    // nodes per bucket (non-pow2; magic div)
#define NB      500                    // 500*200 == N exactly
#define CAP     9936                   // region capacity (x16; mean fill ~9264 +5.5sigma)
#define PBLK    512
#define CHUNK   6250                   // N_EDGES / PBLK exact
#define ELS_CAP 13760                  // >= 6250 + 500*15 = 13750, multiple of 16
#define NLINES  (ELS_CAP / 16)         // 860
#define MROWS   64

// bucket of node d: b = floor(d/200) via magic: (d*671089)>>27  (exact, d<1.86M)
__device__ __forceinline__ unsigned bkt(int d) {
    return (unsigned)(((unsigned long long)(unsigned)d * 671089ull) >> 27);
}

// eop: NB regions of CAP uints (region base 64B-aligned).
// k_sort = cooperative fusion of {partition, build} with one grid sync:
//   phase 1 (partition): packed (src<<8 | dloc) runs, run per (block,bucket)
//   padded to 16-edge (64B) multiples with 0xFFFFFFFF sentinels; block
//   bucket-sorts its chunk in LDS, writes coalesced full 64B lines.
//   phase 2 (build): ONE LDS-atomic pass (rank stashed in bits 25..31),
//   atomic-free compaction to plain src grouped (CSR) by dst node.
// LDS is a union of the two phases' layouts (69.2 KB -> 2 blocks/CU; with
// 512 threads and launch_bounds(512,4) all 512 blocks are co-resident).

struct PShared {                        // partition phase, 69170 B
    int h[512];                         // per-bucket counts (pad to 512)
    int loff[512];                      // exclusive local run offsets
    int resv[NB];                       // global region offsets
    int wsum[8], wpre[8];               // cross-wave scan
    unsigned short owner[NLINES];       // line -> bucket
    unsigned char rank8[CHUNK];         // per-edge rank in its run (<255)
    unsigned int els[ELS_CAP];          // 55 KB staging
};
struct BShared {                        // build phase, 41856 B
    unsigned int els[CAP];              // 39.7 KB
    int cnt[256];
    int off[256];
    int wsum[4], wpre[4];
};
union SortShared { PShared p; BShared b; };

__global__ __launch_bounds__(512, 4) void k_sort(const int* __restrict__ ei,
                                                 int* __restrict__ cursor,
                                                 unsigned int* __restrict__ eop,
                                                 int* __restrict__ nstart,
                                                 int* __restrict__ ndeg,
                                                 float* __restrict__ dinv) {
    __shared__ SortShared sm;
    int t = threadIdx.x;

    // ================= phase 1: partition =================
    {
        sm.p.h[t] = 0;
        __syncthreads();
        int c0 = blockIdx.x * CHUNK;
        const int2* s2 = (const int2*)(ei + c0);
        const int2* d2 = (const int2*)(ei + N_EDGES + c0);
        for (int i = t; i < CHUNK / 2; i += 512) {   // int2 loads: count + rank
            int2 dd = d2[i];
            sm.p.rank8[2 * i]     = (unsigned char)atomicAdd(&sm.p.h[bkt(dd.x)], 1);
            sm.p.rank8[2 * i + 1] = (unsigned char)atomicAdd(&sm.p.h[bkt(dd.y)], 1);
        }
        __syncthreads();
        int cp = (sm.p.h[t] + 15) & ~15;             // run padded to 64B multiple
        int lane = t & 63, w = t >> 6;
        int v = cp;                                  // wave-level inclusive scan
#pragma unroll
        for (int o = 1; o < 64; o <<= 1) {
            int u = __shfl_up(v, o);
            if (lane >= o) v += u;
        }
        if (lane == 63) sm.p.wsum[w] = v;
        __syncthreads();
        if (t < 8) {
            int s = sm.p.wsum[t];
#pragma unroll
            for (int o = 1; o < 8; o <<= 1) {
                int u = __shfl_up(s, o);
                if (t >= o) s += u;
            }
            sm.p.wpre[t] = s;                        // inclusive wave prefix
        }
        __syncthreads();
        int inc = v + ((w > 0) ? sm.p.wpre[w - 1] : 0);   // inclusive over 512
        int totalpad = sm.p.wpre[7];                 // <= ELS_CAP by construction
        int ex = inc - cp;                           // exclusive
        sm.p.loff[t] = ex;
        if (t < NB && cp) {
            sm.p.resv[t] = atomicAdd(&cursor[t], cp);     // stays 16-aligned
            int l0 = ex >> 4;
            for (int k = 0; k < (cp >> 4); ++k) sm.p.owner[l0 + k] = (unsigned short)t;
        }
        for (int i = t; i < totalpad; i += 512) sm.p.els[i] = 0xFFFFFFFFu;  // sentinels
        __syncthreads();
        for (int i = t; i < CHUNK / 2; i += 512) {   // LDS bucket-sort scatter
            int2 ss = s2[i];
            int2 dd = d2[i];                         // L2-hot re-read
            unsigned bx = bkt(dd.x), by = bkt(dd.y);
            sm.p.els[sm.p.loff[bx] + (int)sm.p.rank8[2 * i]] =
                ((unsigned)ss.x << PSH) | (unsigned)(dd.x - (int)(bx * NPB));
            sm.p.els[sm.p.loff[by] + (int)sm.p.rank8[2 * i + 1]] =
                ((unsigned)ss.y << PSH) | (unsigned)(dd.y - (int)(by * NPB));
        }
        __syncthreads();
        for (int i = t; i < totalpad; i += 512) {    // coalesced: full 64B lines
            int b   = sm.p.owner[i >> 4];
            int pos = sm.p.resv[b] + (i - sm.p.loff[b]);
            if (pos < CAP)                           // statistically impossible guard
                eop[(size_t)b * CAP + pos] = sm.p.els[i];
        }
    }

    __threadfence();
    cg::this_grid().sync();

    // ================= phase 2: build =================
    int b = blockIdx.x;
    if (b < NB) {
        if (t < 256) sm.b.cnt[t] = 0;
        __syncthreads();
        int n = cursor[b]; if (n > CAP) n = CAP;     // padded fill; multiple of 16
        unsigned int* reg = eop + (size_t)b * CAP;
        for (int i4 = t; i4 < (n >> 2); i4 += 512) { // stage + count + rank, one pass
            uint4 wv = ((const uint4*)reg)[i4];
            unsigned int e0 = wv.x, e1 = wv.y, e2 = wv.z, e3 = wv.w;
            int r;
            if ((int)e0 >= 0) { r = atomicAdd(&sm.b.cnt[e0 & 0xFF], 1); e0 |= (unsigned)r << 25; }
            if ((int)e1 >= 0) { r = atomicAdd(&sm.b.cnt[e1 & 0xFF], 1); e1 |= (unsigned)r << 25; }
            if ((int)e2 >= 0) { r = atomicAdd(&sm.b.cnt[e2 & 0xFF], 1); e2 |= (unsigned)r << 25; }
            if ((int)e3 >= 0) { r = atomicAdd(&sm.b.cnt[e3 & 0xFF], 1); e3 |= (unsigned)r << 25; }
            ((uint4*)sm.b.els)[i4] = make_uint4(e0, e1, e2, e3);
        }
        __syncthreads();
        int lane = t & 63, w = t >> 6;
        int v = 0;
        if (t < 256) {                               // 4-wave inclusive scan
            v = sm.b.cnt[t];
#pragma unroll
            for (int o = 1; o < 64; o <<= 1) {
                int u = __shfl_up(v, o);
                if (lane >= o) v += u;
            }
            if (lane == 63) sm.b.wsum[w] = v;
        }
        __syncthreads();
        if (t < 4) {
            int s = sm.b.wsum[t];
#pragma unroll
            for (int o = 1; o < 4; o <<= 1) {
                int u = __shfl_up(s, o);
                if (t >= o) s += u;
            }
            sm.b.wpre[t] = s;
        }
        __syncthreads();
        if (t < 256) {
            int val = sm.b.cnt[t];
            int ex = (v + ((w > 0) ? sm.b.wpre[w - 1] : 0)) - val;   // exclusive
            sm.b.off[t] = ex;
            if (t < NPB) {
                int node = b * NPB + t;              // NB*NPB == N exactly
                nstart[node] = b * CAP + ex;
                ndeg[node]   = val;
                dinv[node]   = rsqrtf((float)(val + 1));   // +1 self-loop
            }
        }
        __syncthreads();
        for (int i4 = t; i4 < (n >> 2); i4 += 512) { // rank-addressed compact CSR
            uint4 wv = ((const uint4*)sm.b.els)[i4];
            unsigned int e; unsigned s;
            e = wv.x; s = (e >> PSH) & 0x1FFFFu;
            if (s < N_NODES) reg[sm.b.off[e & 0xFF] + (int)(e >> 25)] = s;
            e = wv.y; s = (e >> PSH) & 0x1FFFFu;
            if (s < N_NODES) reg[sm.b.off[e & 0xFF] + (int)(e >> 25)] = s;
            e = wv.z; s = (e >> PSH) & 0x1FFFFu;
            if (s < N_NODES) reg[sm.b.off[e & 0xFF] + (int)(e >> 25)] = s;
            e = wv.w; s = (e >> PSH) & 0x1FFFFu;
            if (s < N_NODES) reg[sm.b.off[e & 0xFF] + (int)(e >> 25)] = s;
        }
    }
}

// ---- matmul: wave = 64 rows x 4 cols, x in LDS (pad 129), W uniform loads ----
__global__ __launch_bounds__(256) void k_mm1(const float* __restrict__ x,
                                             const float* __restrict__ W1,
                                             const float* __restrict__ dinv,
                                             __half* __restrict__ h1h) {
    __shared__ float sX[MROWS][D_IN + 1];   // 33 KB
    int t = threadIdx.x;
    int r0 = blockIdx.x * MROWS;
    for (int i = t; i < MROWS * (D_IN / 4); i += 256) {
        int row = i >> 5, c4 = i & 31;
        int grow = r0 + row;
        float4 v = (grow < N_NODES) ? ((const float4*)x)[(size_t)grow * 32 + c4]
                                    : make_float4(0.f, 0.f, 0.f, 0.f);
        sX[row][c4 * 4 + 0] = v.x; sX[row][c4 * 4 + 1] = v.y;
        sX[row][c4 * 4 + 2] = v.z; sX[row][c4 * 4 + 3] = v.w;
    }
    __syncthreads();
    int lane = t & 63;
    int c0 = __builtin_amdgcn_readfirstlane((t >> 6) * 4);
    float a0 = 0.f, a1 = 0.f, a2 = 0.f, a3 = 0.f;
#pragma unroll 4
    for (int d = 0; d < D_IN; ++d) {
        float xv = sX[lane][d];
        a0 = fmaf(xv, W1[d * 16 + c0 + 0], a0);
        a1 = fmaf(xv, W1[d * 16 + c0 + 1], a1);
        a2 = fmaf(xv, W1[d * 16 + c0 + 2], a2);
        a3 = fmaf(xv, W1[d * 16 + c0 + 3], a3);
    }
    int grow = r0 + lane;
    if (grow < N_NODES) {
        float di = dinv[grow];
        __half2* o = (__half2*)(h1h + (size_t)grow * H1 + c0);
        o[0] = __floats2half2_rn(a0 * di, a1 * di);
        o[1] = __floats2half2_rn(a2 * di, a3 * di);
    }
}

// ---- layer-1 agg: 8 lanes/node, lane-parallel eop + shfl, half2 gathers,
//      dual accumulator pairs ----
__global__ __launch_bounds__(256) void k_agg1(const unsigned int* __restrict__ eop,
                                              const int* __restrict__ nstart,
                                              const int* __restrict__ ndeg,
                                              const __half* __restrict__ h1h,
                                              const float* __restrict__ dinv,
                                              const float* __restrict__ b1,
                                              const float* __restrict__ W2,
                                              float2* __restrict__ h2f) {
    int t = threadIdx.x;
    int g = t >> 3, l = t & 7;               // 32 groups of 8 lanes
    int base = (t & 63) & ~7;                // wave-relative group base lane
    int node = blockIdx.x * 32 + g;          // 3125*32 == N exactly
    int e0 = nstart[node], deg = ndeg[node];
    const __half2* H = (const __half2*)h1h;  // row = 8 half2
    float a0 = 0.f, a1 = 0.f, c0 = 0.f, c1 = 0.f;
    int nfull = deg & ~7;
    int j = e0;
    for (; j < e0 + nfull; j += 8) {         // 8 edges/group per batch
        int s = (int)eop[j + l];             // coalesced 8-wide per group
#pragma unroll
        for (int k = 0; k < 8; k += 2) {     // dual accum: halve dep chain
            int sk0 = __shfl(s, base + k);
            int sk1 = __shfl(s, base + k + 1);
            float2 f0 = __half22float2(H[sk0 * 8 + l]);
            float2 f1 = __half22float2(H[sk1 * 8 + l]);
            a0 += f0.x; a1 += f0.y;
            c0 += f1.x; c1 += f1.y;
        }
    }
    int r = e0 + deg - j;                    // 0..7 tail
    if (r) {
        int s = (l < r) ? (int)eop[j + l] : -1;
#pragma unroll
        for (int k = 0; k < 8; ++k) {
            int sk = __shfl(s, base + k);
            int su = (sk >= 0) ? sk : 0;
            float m = (sk >= 0) ? 1.f : 0.f;
            float2 f = __half22float2(H[su * 8 + l]);
            a0 = fmaf(f.x, m, a0); a1 = fmaf(f.y, m, a1);
        }
    }
    float di = dinv[node];
    float2 self = __half22float2(H[node * 8 + l]);   // + self-loop
    float s0 = (a0 + c0) + self.x, s1 = (a1 + c1) + self.y;
    float2 bb = ((const float2*)b1)[l];              // b1[2l], b1[2l+1]
    float h0 = fmaxf(fmaf(di, s0, bb.x), 0.f);
    float h1v = fmaxf(fmaf(di, s1, bb.y), 0.f);
    float4 wv = ((const float4*)W2)[l];              // W2 rows 2l, 2l+1
    float p0 = h0 * wv.x + h1v * wv.z;
    float p1 = h0 * wv.y + h1v * wv.w;
#pragma unroll
    for (int off = 1; off < 8; off <<= 1) {
        p0 += __shfl_xor(p0, off);
        p1 += __shfl_xor(p1, off);
    }
    if (l == 0) h2f[node] = make_float2(p0 * di, p1 * di);
}

// ---- layer-2 agg: 4 lanes/node + b2 + log_softmax ----
__global__ __launch_bounds__(256) void k_agg2(const unsigned int* __restrict__ eop,
                                              const int* __restrict__ nstart,
                                              const int* __restrict__ ndeg,
                                              const float2* __restrict__ h2f,
                                              const float* __restrict__ dinv,
                                              const float* __restrict__ b2,
                                              float* __restrict__ out) {
    int tg = blockIdx.x * 256 + threadIdx.x;
    int node = tg >> 2, l = tg & 3;
    if (node >= N_NODES) return;
    int e0 = nstart[node], e1 = e0 + ndeg[node];
    float ax = 0.f, ay = 0.f;
    for (int j = e0 + l; j < e1; j += 4) {
        float2 m = h2f[eop[j]];
        ax += m.x; ay += m.y;
    }
    ax += __shfl_xor(ax, 1); ay += __shfl_xor(ay, 1);
    ax += __shfl_xor(ax, 2); ay += __shfl_xor(ay, 2);
    if (l == 0) {
        float di = dinv[node];
        float2 self = h2f[node];
        float a0 = fmaf(di, ax + self.x, b2[0]);
        float a1 = fmaf(di, ay + self.y, b2[1]);
        float m  = fmaxf(a0, a1);
        float lg = logf(expf(a0 - m) + expf(a1 - m));
        out[2 * node]     = a0 - m - lg;
        out[2 * node + 1] = a1 - m - lg;
    }
}

extern "C" void kernel_launch(void* const* d_in, const int* in_sizes, int n_in,
                              void* d_out, int out_size, void* d_ws, size_t ws_size,
                              hipStream_t stream) {
    const float* x  = (const float*)d_in[0];
    const int*   ei = (const int*)d_in[1];
    const float* W1 = (const float*)d_in[2];
    const float* b1 = (const float*)d_in[3];
    const float* W2 = (const float*)d_in[4];
    const float* b2 = (const float*)d_in[5];
    float* out = (float*)d_out;

    // workspace carve (~25.1 MB); eop base offset 5220352 B = 64B-aligned
    int*          cursor = (int*)d_ws;                       // 512
    int*          nstart = cursor + 512;                     // N (pad 100352)
    int*          ndeg   = nstart + 100352;                  // N (pad 100352)
    float*        dinv   = (float*)(ndeg + 100352);          // N (pad 100352)
    __half*       h1h    = (__half*)(dinv + 100352);         // N*16 halves, 3.2 MB
    float2*       h2f    = (float2*)(h1h + (size_t)100352 * H1);  // N float2
    unsigned int* eop    = (unsigned int*)(h2f + 100352);    // NB*CAP = 19.9 MB

    hipMemsetAsync(cursor, 0, 512 * sizeof(int), stream);    // capture-safe

    {   // cooperative: partition + grid.sync + build
        const int*    a0 = ei;     int*   a1 = cursor;
        unsigned int* a2 = eop;    int*   a3 = nstart;
        int*          a4 = ndeg;   float* a5 = dinv;
        void* ka[6] = { &a0, &a1, &a2, &a3, &a4, &a5 };
        hipLaunchCooperativeKernel((const void*)k_sort, dim3(PBLK), dim3(512),
                                   ka, 0, stream);
    }

    k_mm1 <<<(N_NODES + MROWS - 1) / MROWS, 256, 0, stream>>>(x, W1, dinv, h1h);
    k_agg1<<<N_NODES / 32, 256, 0, stream>>>(eop, nstart, ndeg, h1h, dinv, b1, W2, h2f);
    k_agg2<<<(N_NODES * 4 + 255) / 256, 256, 0, stream>>>(eop, nstart, ndeg, h2f, dinv, b2, out);
}

// Round 6
// 268.115 us; speedup vs baseline: 1.3058x; 1.3058x over previous
//
#include <hip/hip_runtime.h>
#include <hip/hip_fp16.h>
#include <math.h>

#define N_NODES 100000
#define N_EDGES 3200000
#define D_IN    128
#define H1      16

#define PSH     8                      // packing shift: (src<<8 | dloc), dloc < 256
#define NPB     200                    // nodes per bucket (non-pow2; magic div)
#define NB      500                    // 500*200 == N exactly
#define CAP     9936                   // region capacity (x16; mean fill ~9264 +5.5sigma)
#define PBLK    512
#define CHUNK   6250                   // N_EDGES / PBLK exact
#define ELS_CAP 13760                  // >= 6250 + 500*15 = 13750, multiple of 16
#define NLINES  (ELS_CAP / 16)         // 860
#define MROWS   64
#define CSTRIDE 32                     // cursor stride in ints: 1 counter per 128B line

// bucket of node d: b = floor(d/200) via magic: (d*671089)>>27  (exact, d<1.86M)
__device__ __forceinline__ unsigned bkt(int d) {
    return (unsigned)(((unsigned long long)(unsigned)d * 671089ull) >> 27);
}

// eop: NB regions of CAP uints (region base 64B-aligned).
// k_sort = fused {partition, build} with a HAND-ROLLED grid barrier (no
// cooperative launch: round-5 showed cg::grid().sync() + coop graph node cost
// ~200us on this chip). Residency proof for the barrier: LDS 69.2KB -> 2
// blocks/CU; launch_bounds(512,4) caps VGPR<=128 (measured 52); grid = 512 =
// 2 * 256 CUs exactly, so all blocks are co-resident and the spin cannot
// deadlock. cursor counters are strided 1-per-128B-line to kill same-line
// device-atomic serialization (500 parallel lines vs 16 hot ones).
//   phase 1 (partition): packed (src<<8 | dloc) runs, per (block,bucket),
//   padded to 16-edge (64B) multiples with 0xFFFFFFFF sentinels; block
//   bucket-sorts its chunk in LDS, writes coalesced full 64B lines.
//   phase 2 (build): ONE LDS-atomic pass (rank stashed in bits 25..31),
//   atomic-free compaction to plain src grouped (CSR) by dst node.

struct PShared {                        // partition phase, 69170 B
    int h[512];                         // per-bucket counts (pad to 512)
    int loff[512];                      // exclusive local run offsets
    int resv[NB];                       // global region offsets
    int wsum[8], wpre[8];               // cross-wave scan
    unsigned short owner[NLINES];       // line -> bucket
    unsigned char rank8[CHUNK];         // per-edge rank in its run (<255)
    unsigned int els[ELS_CAP];          // 55 KB staging
};
struct BShared {                        // build phase, 41856 B
    unsigned int els[CAP];              // 39.7 KB
    int cnt[256];
    int off[256];
    int wsum[4], wpre[4];
};
union SortShared { PShared p; BShared b; };

__global__ __launch_bounds__(512, 4) void k_sort(const int* __restrict__ ei,
                                                 int* __restrict__ cursor,
                                                 unsigned int* __restrict__ eop,
                                                 int* __restrict__ nstart,
                                                 int* __restrict__ ndeg,
                                                 float* __restrict__ dinv,
                                                 unsigned int* __restrict__ bar) {
    __shared__ SortShared sm;
    int t = threadIdx.x;

    // ================= phase 1: partition =================
    {
        sm.p.h[t] = 0;
        __syncthreads();
        int c0 = blockIdx.x * CHUNK;
        const int2* s2 = (const int2*)(ei + c0);
        const int2* d2 = (const int2*)(ei + N_EDGES + c0);
        for (int i = t; i < CHUNK / 2; i += 512) {   // int2 loads: count + rank
            int2 dd = d2[i];
            sm.p.rank8[2 * i]     = (unsigned char)atomicAdd(&sm.p.h[bkt(dd.x)], 1);
            sm.p.rank8[2 * i + 1] = (unsigned char)atomicAdd(&sm.p.h[bkt(dd.y)], 1);
        }
        __syncthreads();
        int cp = (sm.p.h[t] + 15) & ~15;             // run padded to 64B multiple
        int lane = t & 63, w = t >> 6;
        int v = cp;                                  // wave-level inclusive scan
#pragma unroll
        for (int o = 1; o < 64; o <<= 1) {
            int u = __shfl_up(v, o);
            if (lane >= o) v += u;
        }
        if (lane == 63) sm.p.wsum[w] = v;
        __syncthreads();
        if (t < 8) {
            int s = sm.p.wsum[t];
#pragma unroll
            for (int o = 1; o < 8; o <<= 1) {
                int u = __shfl_up(s, o);
                if (t >= o) s += u;
            }
            sm.p.wpre[t] = s;                        // inclusive wave prefix
        }
        __syncthreads();
        int inc = v + ((w > 0) ? sm.p.wpre[w - 1] : 0);   // inclusive over 512
        int totalpad = sm.p.wpre[7];                 // <= ELS_CAP by construction
        int ex = inc - cp;                           // exclusive
        sm.p.loff[t] = ex;
        if (t < NB && cp) {
            sm.p.resv[t] = atomicAdd(&cursor[t * CSTRIDE], cp);  // 16-aligned; 1 line/counter
            int l0 = ex >> 4;
            for (int k = 0; k < (cp >> 4); ++k) sm.p.owner[l0 + k] = (unsigned short)t;
        }
        for (int i = t; i < totalpad; i += 512) sm.p.els[i] = 0xFFFFFFFFu;  // sentinels
        __syncthreads();
        for (int i = t; i < CHUNK / 2; i += 512) {   // LDS bucket-sort scatter
            int2 ss = s2[i];
            int2 dd = d2[i];                         // L2-hot re-read
            unsigned bx = bkt(dd.x), by = bkt(dd.y);
            sm.p.els[sm.p.loff[bx] + (int)sm.p.rank8[2 * i]] =
                ((unsigned)ss.x << PSH) | (unsigned)(dd.x - (int)(bx * NPB));
            sm.p.els[sm.p.loff[by] + (int)sm.p.rank8[2 * i + 1]] =
                ((unsigned)ss.y << PSH) | (unsigned)(dd.y - (int)(by * NPB));
        }
        __syncthreads();
        for (int i = t; i < totalpad; i += 512) {    // coalesced: full 64B lines
            int b   = sm.p.owner[i >> 4];
            int pos = sm.p.resv[b] + (i - sm.p.loff[b]);
            if (pos < CAP)                           // statistically impossible guard
                eop[(size_t)b * CAP + pos] = sm.p.els[i];
        }
    }

    // ========== hand-rolled grid barrier (all 512 blocks co-resident) ==========
    __syncthreads();
    if (t == 0) {
        __threadfence();                             // flush this block's writes device-wide
        atomicAdd(bar, 1u);                          // device-scope arrive
        while (__hip_atomic_load(bar, __ATOMIC_ACQUIRE, __HIP_MEMORY_SCOPE_AGENT) < PBLK)
            __builtin_amdgcn_s_sleep(8);             // backoff poll
    }
    __syncthreads();

    // ================= phase 2: build =================
    int b = blockIdx.x;
    if (b < NB) {
        if (t < 256) sm.b.cnt[t] = 0;
        __syncthreads();
        int n = __hip_atomic_load(&cursor[b * CSTRIDE], __ATOMIC_RELAXED,
                                  __HIP_MEMORY_SCOPE_AGENT);   // coherent read
        if (n > CAP) n = CAP;                        // padded fill; multiple of 16
        unsigned int* reg = eop + (size_t)b * CAP;
        for (int i4 = t; i4 < (n >> 2); i4 += 512) { // stage + count + rank, one pass
            uint4 wv = ((const uint4*)reg)[i4];
            unsigned int e0 = wv.x, e1 = wv.y, e2 = wv.z, e3 = wv.w;
            int r;
            if ((int)e0 >= 0) { r = atomicAdd(&sm.b.cnt[e0 & 0xFF], 1); e0 |= (unsigned)r << 25; }
            if ((int)e1 >= 0) { r = atomicAdd(&sm.b.cnt[e1 & 0xFF], 1); e1 |= (unsigned)r << 25; }
            if ((int)e2 >= 0) { r = atomicAdd(&sm.b.cnt[e2 & 0xFF], 1); e2 |= (unsigned)r << 25; }
            if ((int)e3 >= 0) { r = atomicAdd(&sm.b.cnt[e3 & 0xFF], 1); e3 |= (unsigned)r << 25; }
            ((uint4*)sm.b.els)[i4] = make_uint4(e0, e1, e2, e3);
        }
        __syncthreads();
        int lane = t & 63, w = t >> 6;
        int v = 0;
        if (t < 256) {                               // 4-wave inclusive scan
            v = sm.b.cnt[t];
#pragma unroll
            for (int o = 1; o < 64; o <<= 1) {
                int u = __shfl_up(v, o);
                if (lane >= o) v += u;
            }
            if (lane == 63) sm.b.wsum[w] = v;
        }
        __syncthreads();
        if (t < 4) {
            int s = sm.b.wsum[t];
#pragma unroll
            for (int o = 1; o < 4; o <<= 1) {
                int u = __shfl_up(s, o);
                if (t >= o) s += u;
            }
            sm.b.wpre[t] = s;
        }
        __syncthreads();
        if (t < 256) {
            int val = sm.b.cnt[t];
            int ex = (v + ((w > 0) ? sm.b.wpre[w - 1] : 0)) - val;   // exclusive
            sm.b.off[t] = ex;
            if (t < NPB) {
                int node = b * NPB + t;              // NB*NPB == N exactly
                nstart[node] = b * CAP + ex;
                ndeg[node]   = val;
                dinv[node]   = rsqrtf((float)(val + 1));   // +1 self-loop
            }
        }
        __syncthreads();
        for (int i4 = t; i4 < (n >> 2); i4 += 512) { // rank-addressed compact CSR
            uint4 wv = ((const uint4*)sm.b.els)[i4];
            unsigned int e; unsigned s;
            e = wv.x; s = (e >> PSH) & 0x1FFFFu;
            if (s < N_NODES) reg[sm.b.off[e & 0xFF] + (int)(e >> 25)] = s;
            e = wv.y; s = (e >> PSH) & 0x1FFFFu;
            if (s < N_NODES) reg[sm.b.off[e & 0xFF] + (int)(e >> 25)] = s;
            e = wv.z; s = (e >> PSH) & 0x1FFFFu;
            if (s < N_NODES) reg[sm.b.off[e & 0xFF] + (int)(e >> 25)] = s;
            e = wv.w; s = (e >> PSH) & 0x1FFFFu;
            if (s < N_NODES) reg[sm.b.off[e & 0xFF] + (int)(e >> 25)] = s;
        }
    }
}

// ---- matmul: wave = 64 rows x 4 cols, x in LDS (pad 129), W uniform loads ----
__global__ __launch_bounds__(256) void k_mm1(const float* __restrict__ x,
                                             const float* __restrict__ W1,
                                             const float* __restrict__ dinv,
                                             __half* __restrict__ h1h) {
    __shared__ float sX[MROWS][D_IN + 1];   // 33 KB
    int t = threadIdx.x;
    int r0 = blockIdx.x * MROWS;
    for (int i = t; i < MROWS * (D_IN / 4); i += 256) {
        int row = i >> 5, c4 = i & 31;
        int grow = r0 + row;
        float4 v = (grow < N_NODES) ? ((const float4*)x)[(size_t)grow * 32 + c4]
                                    : make_float4(0.f, 0.f, 0.f, 0.f);
        sX[row][c4 * 4 + 0] = v.x; sX[row][c4 * 4 + 1] = v.y;
        sX[row][c4 * 4 + 2] = v.z; sX[row][c4 * 4 + 3] = v.w;
    }
    __syncthreads();
    int lane = t & 63;
    int c0 = __builtin_amdgcn_readfirstlane((t >> 6) * 4);
    float a0 = 0.f, a1 = 0.f, a2 = 0.f, a3 = 0.f;
#pragma unroll 4
    for (int d = 0; d < D_IN; ++d) {
        float xv = sX[lane][d];
        a0 = fmaf(xv, W1[d * 16 + c0 + 0], a0);
        a1 = fmaf(xv, W1[d * 16 + c0 + 1], a1);
        a2 = fmaf(xv, W1[d * 16 + c0 + 2], a2);
        a3 = fmaf(xv, W1[d * 16 + c0 + 3], a3);
    }
    int grow = r0 + lane;
    if (grow < N_NODES) {
        float di = dinv[grow];
        __half2* o = (__half2*)(h1h + (size_t)grow * H1 + c0);
        o[0] = __floats2half2_rn(a0 * di, a1 * di);
        o[1] = __floats2half2_rn(a2 * di, a3 * di);
    }
}

// ---- layer-1 agg: 8 lanes/node, lane-parallel eop + shfl, half2 gathers,
//      dual accumulator pairs ----
__global__ __launch_bounds__(256) void k_agg1(const unsigned int* __restrict__ eop,
                                              const int* __restrict__ nstart,
                                              const int* __restrict__ ndeg,
                                              const __half* __restrict__ h1h,
                                              const float* __restrict__ dinv,
                                              const float* __restrict__ b1,
                                              const float* __restrict__ W2,
                                              float2* __restrict__ h2f) {
    int t = threadIdx.x;
    int g = t >> 3, l = t & 7;               // 32 groups of 8 lanes
    int base = (t & 63) & ~7;                // wave-relative group base lane
    int node = blockIdx.x * 32 + g;          // 3125*32 == N exactly
    int e0 = nstart[node], deg = ndeg[node];
    const __half2* H = (const __half2*)h1h;  // row = 8 half2
    float a0 = 0.f, a1 = 0.f, c0 = 0.f, c1 = 0.f;
    int nfull = deg & ~7;
    int j = e0;
    for (; j < e0 + nfull; j += 8) {         // 8 edges/group per batch
        int s = (int)eop[j + l];             // coalesced 8-wide per group
#pragma unroll
        for (int k = 0; k < 8; k += 2) {     // dual accum: halve dep chain
            int sk0 = __shfl(s, base + k);
            int sk1 = __shfl(s, base + k + 1);
            float2 f0 = __half22float2(H[sk0 * 8 + l]);
            float2 f1 = __half22float2(H[sk1 * 8 + l]);
            a0 += f0.x; a1 += f0.y;
            c0 += f1.x; c1 += f1.y;
        }
    }
    int r = e0 + deg - j;                    // 0..7 tail
    if (r) {
        int s = (l < r) ? (int)eop[j + l] : -1;
#pragma unroll
        for (int k = 0; k < 8; ++k) {
            int sk = __shfl(s, base + k);
            int su = (sk >= 0) ? sk : 0;
            float m = (sk >= 0) ? 1.f : 0.f;
            float2 f = __half22float2(H[su * 8 + l]);
            a0 = fmaf(f.x, m, a0); a1 = fmaf(f.y, m, a1);
        }
    }
    float di = dinv[node];
    float2 self = __half22float2(H[node * 8 + l]);   // + self-loop
    float s0 = (a0 + c0) + self.x, s1 = (a1 + c1) + self.y;
    float2 bb = ((const float2*)b1)[l];              // b1[2l], b1[2l+1]
    float h0 = fmaxf(fmaf(di, s0, bb.x), 0.f);
    float h1v = fmaxf(fmaf(di, s1, bb.y), 0.f);
    float4 wv = ((const float4*)W2)[l];              // W2 rows 2l, 2l+1
    float p0 = h0 * wv.x + h1v * wv.z;
    float p1 = h0 * wv.y + h1v * wv.w;
#pragma unroll
    for (int off = 1; off < 8; off <<= 1) {
        p0 += __shfl_xor(p0, off);
        p1 += __shfl_xor(p1, off);
    }
    if (l == 0) h2f[node] = make_float2(p0 * di, p1 * di);
}

// ---- layer-2 agg: 4 lanes/node + b2 + log_softmax ----
__global__ __launch_bounds__(256) void k_agg2(const unsigned int* __restrict__ eop,
                                              const int* __restrict__ nstart,
                                              const int* __restrict__ ndeg,
                                              const float2* __restrict__ h2f,
                                              const float* __restrict__ dinv,
                                              const float* __restrict__ b2,
                                              float* __restrict__ out) {
    int tg = blockIdx.x * 256 + threadIdx.x;
    int node = tg >> 2, l = tg & 3;
    if (node >= N_NODES) return;
    int e0 = nstart[node], e1 = e0 + ndeg[node];
    float ax = 0.f, ay = 0.f;
    for (int j = e0 + l; j < e1; j += 4) {
        float2 m = h2f[eop[j]];
        ax += m.x; ay += m.y;
    }
    ax += __shfl_xor(ax, 1); ay += __shfl_xor(ay, 1);
    ax += __shfl_xor(ax, 2); ay += __shfl_xor(ay, 2);
    if (l == 0) {
        float di = dinv[node];
        float2 self = h2f[node];
        float a0 = fmaf(di, ax + self.x, b2[0]);
        float a1 = fmaf(di, ay + self.y, b2[1]);
        float m  = fmaxf(a0, a1);
        float lg = logf(expf(a0 - m) + expf(a1 - m));
        out[2 * node]     = a0 - m - lg;
        out[2 * node + 1] = a1 - m - lg;
    }
}

extern "C" void kernel_launch(void* const* d_in, const int* in_sizes, int n_in,
                              void* d_out, int out_size, void* d_ws, size_t ws_size,
                              hipStream_t stream) {
    const float* x  = (const float*)d_in[0];
    const int*   ei = (const int*)d_in[1];
    const float* W1 = (const float*)d_in[2];
    const float* b1 = (const float*)d_in[3];
    const float* W2 = (const float*)d_in[4];
    const float* b2 = (const float*)d_in[5];
    float* out = (float*)d_out;

    // workspace carve (~25.2 MB); eop base offset 5284096 B = 64B-aligned
    int*          cursor = (int*)d_ws;                       // 500 counters, stride 32 ints
    unsigned int* bar    = (unsigned int*)(cursor + 16384);  // grid-barrier flag
    int*          nstart = cursor + 16448;                   // N (pad 100352)
    int*          ndeg   = nstart + 100352;                  // N (pad 100352)
    float*        dinv   = (float*)(ndeg + 100352);          // N (pad 100352)
    __half*       h1h    = (__half*)(dinv + 100352);         // N*16 halves, 3.2 MB
    float2*       h2f    = (float2*)(h1h + (size_t)100352 * H1);  // N float2
    unsigned int* eop    = (unsigned int*)(h2f + 100352);    // NB*CAP = 19.9 MB

    hipMemsetAsync(cursor, 0, 16448 * sizeof(int), stream);  // counters + bar, capture-safe

    k_sort<<<PBLK, 512, 0, stream>>>(ei, cursor, eop, nstart, ndeg, dinv, bar);
    k_mm1 <<<(N_NODES + MROWS - 1) / MROWS, 256, 0, stream>>>(x, W1, dinv, h1h);
    k_agg1<<<N_NODES / 32, 256, 0, stream>>>(eop, nstart, ndeg, h1h, dinv, b1, W2, h2f);
    k_agg2<<<(N_NODES * 4 + 255) / 256, 256, 0, stream>>>(eop, nstart, ndeg, h2f, dinv, b2, out);
}

// Round 7
// 223.823 us; speedup vs baseline: 1.5642x; 1.1979x over previous
//
#include <hip/hip_runtime.h>
#include <hip/hip_fp16.h>
#include <math.h>

#define N_NODES 100000
#define N_EDGES 3200000
#define D_IN    128
#define H1      16

#define PSH     8                      // packing shift: (src<<8 | dloc), dloc < 256
#define NPB     200                    // nodes per bucket (non-pow2; magic div)
#define NB      500                    // 500*200 == N exactly
#define CAP     9936                   // region capacity (x16; mean fill ~9264 +5.5sigma)
#define PBLK    512
#define CHUNK   6250                   // N_EDGES / PBLK exact
#define ELS_CAP 13760                  // >= 6250 + 500*15 = 13750, multiple of 16
#define NLINES  (ELS_CAP / 16)         // 860
#define CSTRIDE 32                     // cursor stride in ints: 1 counter per 128B line
#define MMR     196                    // rows of x@W1 per partition block (512*196 >= N)

// bucket of node d: b = floor(d/200) via magic: (d*671089)>>27  (exact, d<1.86M)
__device__ __forceinline__ unsigned bkt(int d) {
    return (unsigned)(((unsigned long long)(unsigned)d * 671089ull) >> 27);
}

// Pipeline (split kernels — fusion w/ grid sync measured 60-150us worse, r5/r6):
//   k_partition: bucket-sort edges into eop runs + TAIL: h1u = x@W1 UNSCALED
//                (mm needs no dinv; dinv[src] applied in agg1 at gather time)
//   k_build:     per-region count/scan/compact -> CSR + ndeg/nstart/dinv
//   k_agg1:      gather h1u[src]*dinv[src], relu, fused W2 -> h2f (prescaled)
//   k_agg2:      8 lanes/node gather h2f, b2 + log_softmax
// eop: NB regions of CAP uints; runs padded to 16-edge (64B) lines with
// 0xFFFFFFFF sentinels; coalesced full-line writeout.

__global__ __launch_bounds__(512) void k_partition(const int* __restrict__ ei,
                                                   int* __restrict__ cursor,
                                                   unsigned int* __restrict__ eop,
                                                   const float* __restrict__ x,
                                                   const float* __restrict__ W1,
                                                   __half* __restrict__ h1u) {
    __shared__ int h[512];                       // per-bucket counts (pad to 512)
    __shared__ int loff[512];                    // exclusive local run offsets
    __shared__ int resv[NB];                     // global region offsets
    __shared__ int wsum[8], wpre[8];             // cross-wave scan
    __shared__ unsigned short owner[NLINES];     // line -> bucket
    __shared__ unsigned char rank8[CHUNK];       // per-edge rank in its run (<255)
    __shared__ unsigned int els[ELS_CAP];        // 55 KB staging (reused by mm tail)
    int t = threadIdx.x;
    h[t] = 0;
    __syncthreads();
    int c0e = blockIdx.x * CHUNK;
    const int2* s2 = (const int2*)(ei + c0e);
    const int2* d2 = (const int2*)(ei + N_EDGES + c0e);
    for (int i = t; i < CHUNK / 2; i += 512) {   // int2 loads: count + rank
        int2 dd = d2[i];
        rank8[2 * i]     = (unsigned char)atomicAdd(&h[bkt(dd.x)], 1);
        rank8[2 * i + 1] = (unsigned char)atomicAdd(&h[bkt(dd.y)], 1);
    }
    __syncthreads();
    int cp = (h[t] + 15) & ~15;                  // run padded to 64B multiple
    int lane = t & 63, w = t >> 6;
    int v = cp;                                  // wave-level inclusive scan
#pragma unroll
    for (int o = 1; o < 64; o <<= 1) {
        int u = __shfl_up(v, o);
        if (lane >= o) v += u;
    }
    if (lane == 63) wsum[w] = v;
    __syncthreads();
    if (t < 8) {
        int s = wsum[t];
#pragma unroll
        for (int o = 1; o < 8; o <<= 1) {
            int u = __shfl_up(s, o);
            if (t >= o) s += u;
        }
        wpre[t] = s;                             // inclusive wave prefix
    }
    __syncthreads();
    int inc = v + ((w > 0) ? wpre[w - 1] : 0);   // inclusive over 512
    int totalpad = wpre[7];                      // <= ELS_CAP by construction
    int ex = inc - cp;                           // exclusive
    loff[t] = ex;
    if (t < NB && cp) {
        resv[t] = atomicAdd(&cursor[t * CSTRIDE], cp);  // 16-aligned
        int l0 = ex >> 4;
        for (int k = 0; k < (cp >> 4); ++k) owner[l0 + k] = (unsigned short)t;
    }
    for (int i = t; i < totalpad; i += 512) els[i] = 0xFFFFFFFFu;   // sentinels
    __syncthreads();
    for (int i = t; i < CHUNK / 2; i += 512) {   // LDS bucket-sort scatter
        int2 ss = s2[i];
        int2 dd = d2[i];                         // L2-hot re-read
        unsigned bx = bkt(dd.x), by = bkt(dd.y);
        els[loff[bx] + (int)rank8[2 * i]] =
            ((unsigned)ss.x << PSH) | (unsigned)(dd.x - (int)(bx * NPB));
        els[loff[by] + (int)rank8[2 * i + 1]] =
            ((unsigned)ss.y << PSH) | (unsigned)(dd.y - (int)(by * NPB));
    }
    __syncthreads();
    for (int i = t; i < totalpad; i += 512) {    // coalesced: full 64B lines
        int b   = owner[i >> 4];
        int pos = resv[b] + (i - loff[b]);
        if (pos < CAP)                           // statistically impossible guard
            eop[(size_t)b * CAP + pos] = els[i];
    }

    // ---- mm tail: h1u = x @ W1 (UNSCALED), rows [b*MMR, b*MMR+MMR) ----
    // reuses els LDS as 64x129 f32 tile (33KB); 8 waves x 2 cols each.
    float (*sXf)[D_IN + 1] = (float (*)[D_IN + 1])els;
    int cc = __builtin_amdgcn_readfirstlane(2 * w);      // wave's column pair
    int rbase = blockIdx.x * MMR;
    for (int p = 0; p < 4; ++p) {                // 4 passes of 64 rows (last: 4)
        int pb = rbase + p * 64;
        __syncthreads();                         // previous pass / els reads done
        for (int i = t; i < 64 * 32; i += 512) {
            int row = i >> 5, c4 = i & 31;
            int grow = pb + row;
            float4 vv = (grow < N_NODES) ? ((const float4*)x)[(size_t)grow * 32 + c4]
                                         : make_float4(0.f, 0.f, 0.f, 0.f);
            sXf[row][c4 * 4 + 0] = vv.x; sXf[row][c4 * 4 + 1] = vv.y;
            sXf[row][c4 * 4 + 2] = vv.z; sXf[row][c4 * 4 + 3] = vv.w;
        }
        __syncthreads();
        int lrow = p * 64 + lane;
        int grow = pb + lane;
        if (lrow < MMR && grow < N_NODES) {
            float a0 = 0.f, a1 = 0.f;
#pragma unroll 4
            for (int d = 0; d < D_IN; ++d) {
                float xv = sXf[lane][d];
                a0 = fmaf(xv, W1[d * 16 + cc], a0);
                a1 = fmaf(xv, W1[d * 16 + cc + 1], a1);
            }
            ((__half2*)h1u)[(size_t)grow * 8 + w] = __floats2half2_rn(a0, a1);
        }
    }
}

// ---- build: uint4 stage, single count+rank atomic pass, atomic-free compaction ----
__global__ __launch_bounds__(512) void k_build(const int* __restrict__ cursor,
                                               unsigned int* __restrict__ eop,
                                               int* __restrict__ nstart,
                                               int* __restrict__ ndeg,
                                               float* __restrict__ dinv) {
    __shared__ unsigned int els[CAP];   // 39.7 KB
    __shared__ int cnt[256];
    __shared__ int off[256];
    __shared__ int wsum[4], wpre[4];
    int t = threadIdx.x, b = blockIdx.x;
    if (t < 256) cnt[t] = 0;
    __syncthreads();
    int n = cursor[b * CSTRIDE]; if (n > CAP) n = CAP;   // padded fill; mult of 16
    unsigned int* reg = eop + (size_t)b * CAP;
    for (int i4 = t; i4 < (n >> 2); i4 += 512) { // stage + count + rank, one pass
        uint4 wv = ((const uint4*)reg)[i4];
        unsigned int e0 = wv.x, e1 = wv.y, e2 = wv.z, e3 = wv.w;
        int r;
        if ((int)e0 >= 0) { r = atomicAdd(&cnt[e0 & 0xFF], 1); e0 |= (unsigned)r << 25; }
        if ((int)e1 >= 0) { r = atomicAdd(&cnt[e1 & 0xFF], 1); e1 |= (unsigned)r << 25; }
        if ((int)e2 >= 0) { r = atomicAdd(&cnt[e2 & 0xFF], 1); e2 |= (unsigned)r << 25; }
        if ((int)e3 >= 0) { r = atomicAdd(&cnt[e3 & 0xFF], 1); e3 |= (unsigned)r << 25; }
        ((uint4*)els)[i4] = make_uint4(e0, e1, e2, e3);
    }
    __syncthreads();
    int lane = t & 63, w = t >> 6;
    int v = 0;
    if (t < 256) {                               // 4-wave inclusive scan
        v = cnt[t];
#pragma unroll
        for (int o = 1; o < 64; o <<= 1) {
            int u = __shfl_up(v, o);
            if (lane >= o) v += u;
        }
        if (lane == 63) wsum[w] = v;
    }
    __syncthreads();
    if (t < 4) {
        int s = wsum[t];
#pragma unroll
        for (int o = 1; o < 4; o <<= 1) {
            int u = __shfl_up(s, o);
            if (t >= o) s += u;
        }
        wpre[t] = s;
    }
    __syncthreads();
    if (t < 256) {
        int val = cnt[t];
        int ex = (v + ((w > 0) ? wpre[w - 1] : 0)) - val;   // exclusive
        off[t] = ex;
        if (t < NPB) {
            int node = b * NPB + t;              // NB*NPB == N exactly
            nstart[node] = b * CAP + ex;
            ndeg[node]   = val;
            dinv[node]   = rsqrtf((float)(val + 1));   // +1 self-loop
        }
    }
    __syncthreads();
    for (int i4 = t; i4 < (n >> 2); i4 += 512) { // rank-addressed compact CSR
        uint4 wv = ((const uint4*)els)[i4];
        unsigned int e; unsigned s;
        e = wv.x; s = (e >> PSH) & 0x1FFFFu;
        if (s < N_NODES) reg[off[e & 0xFF] + (int)(e >> 25)] = s;
        e = wv.y; s = (e >> PSH) & 0x1FFFFu;
        if (s < N_NODES) reg[off[e & 0xFF] + (int)(e >> 25)] = s;
        e = wv.z; s = (e >> PSH) & 0x1FFFFu;
        if (s < N_NODES) reg[off[e & 0xFF] + (int)(e >> 25)] = s;
        e = wv.w; s = (e >> PSH) & 0x1FFFFu;
        if (s < N_NODES) reg[off[e & 0xFF] + (int)(e >> 25)] = s;
    }
}

// ---- layer-1 agg: 8 lanes/node, lane-parallel eop + shfl, half2 gathers,
//      dinv[src] applied at gather (h1u is unscaled), dual accumulators ----
__global__ __launch_bounds__(256) void k_agg1(const unsigned int* __restrict__ eop,
                                              const int* __restrict__ nstart,
                                              const int* __restrict__ ndeg,
                                              const __half* __restrict__ h1u,
                                              const float* __restrict__ dinv,
                                              const float* __restrict__ b1,
                                              const float* __restrict__ W2,
                                              float2* __restrict__ h2f) {
    int t = threadIdx.x;
    int g = t >> 3, l = t & 7;               // 32 groups of 8 lanes
    int base = (t & 63) & ~7;                // wave-relative group base lane
    int node = blockIdx.x * 32 + g;          // 3125*32 == N exactly
    int e0 = nstart[node], deg = ndeg[node];
    const __half2* H = (const __half2*)h1u;  // row = 8 half2
    float a0 = 0.f, a1 = 0.f, c0 = 0.f, c1 = 0.f;
    int nfull = deg & ~7;
    int j = e0;
    for (; j < e0 + nfull; j += 8) {         // 8 edges/group per batch
        int s = (int)eop[j + l];             // coalesced 8-wide per group
#pragma unroll
        for (int k = 0; k < 8; k += 2) {     // dual accum: halve dep chain
            int sk0 = __shfl(s, base + k);
            int sk1 = __shfl(s, base + k + 1);
            float dv0 = dinv[sk0];           // same addr across group: broadcast
            float dv1 = dinv[sk1];
            float2 f0 = __half22float2(H[sk0 * 8 + l]);
            float2 f1 = __half22float2(H[sk1 * 8 + l]);
            a0 = fmaf(f0.x, dv0, a0); a1 = fmaf(f0.y, dv0, a1);
            c0 = fmaf(f1.x, dv1, c0); c1 = fmaf(f1.y, dv1, c1);
        }
    }
    int r = e0 + deg - j;                    // 0..7 tail
    if (r) {
        int s = (l < r) ? (int)eop[j + l] : -1;
#pragma unroll
        for (int k = 0; k < 8; ++k) {
            int sk = __shfl(s, base + k);
            int su = (sk >= 0) ? sk : 0;
            float dv = (sk >= 0) ? dinv[su] : 0.f;
            float2 f = __half22float2(H[su * 8 + l]);
            a0 = fmaf(f.x, dv, a0); a1 = fmaf(f.y, dv, a1);
        }
    }
    float di = dinv[node];
    float2 self = __half22float2(H[node * 8 + l]);   // self-loop: * dinv[node]
    float s0 = (a0 + c0) + self.x * di, s1 = (a1 + c1) + self.y * di;
    float2 bb = ((const float2*)b1)[l];              // b1[2l], b1[2l+1]
    float h0 = fmaxf(fmaf(di, s0, bb.x), 0.f);
    float h1v = fmaxf(fmaf(di, s1, bb.y), 0.f);
    float4 wv = ((const float4*)W2)[l];              // W2 rows 2l, 2l+1
    float p0 = h0 * wv.x + h1v * wv.z;
    float p1 = h0 * wv.y + h1v * wv.w;
#pragma unroll
    for (int off = 1; off < 8; off <<= 1) {
        p0 += __shfl_xor(p0, off);
        p1 += __shfl_xor(p1, off);
    }
    if (l == 0) h2f[node] = make_float2(p0 * di, p1 * di);
}

// ---- layer-2 agg: 8 lanes/node + b2 + log_softmax ----
__global__ __launch_bounds__(256) void k_agg2(const unsigned int* __restrict__ eop,
                                              const int* __restrict__ nstart,
                                              const int* __restrict__ ndeg,
                                              const float2* __restrict__ h2f,
                                              const float* __restrict__ dinv,
                                              const float* __restrict__ b2,
                                              float* __restrict__ out) {
    int tg = blockIdx.x * 256 + threadIdx.x;
    int node = tg >> 3, l = tg & 7;          // 3125*256/8 == N exactly
    int e0 = nstart[node], e1 = e0 + ndeg[node];
    float ax = 0.f, ay = 0.f;
    for (int j = e0 + l; j < e1; j += 8) {
        float2 m = h2f[eop[j]];
        ax += m.x; ay += m.y;
    }
    ax += __shfl_xor(ax, 1); ay += __shfl_xor(ay, 1);
    ax += __shfl_xor(ax, 2); ay += __shfl_xor(ay, 2);
    ax += __shfl_xor(ax, 4); ay += __shfl_xor(ay, 4);
    if (l == 0) {
        float di = dinv[node];
        float2 self = h2f[node];
        float a0 = fmaf(di, ax + self.x, b2[0]);
        float a1 = fmaf(di, ay + self.y, b2[1]);
        float m  = fmaxf(a0, a1);
        float lg = logf(expf(a0 - m) + expf(a1 - m));
        out[2 * node]     = a0 - m - lg;
        out[2 * node + 1] = a1 - m - lg;
    }
}

extern "C" void kernel_launch(void* const* d_in, const int* in_sizes, int n_in,
                              void* d_out, int out_size, void* d_ws, size_t ws_size,
                              hipStream_t stream) {
    const float* x  = (const float*)d_in[0];
    const int*   ei = (const int*)d_in[1];
    const float* W1 = (const float*)d_in[2];
    const float* b1 = (const float*)d_in[3];
    const float* W2 = (const float*)d_in[4];
    const float* b2 = (const float*)d_in[5];
    float* out = (float*)d_out;

    // workspace carve (~25.2 MB); eop base offset 5283840 B = 64B-aligned
    int*          cursor = (int*)d_ws;                       // 500 ctrs, stride 32 ints
    int*          nstart = cursor + 16384;                   // N (pad 100352)
    int*          ndeg   = nstart + 100352;                  // N (pad 100352)
    float*        dinv   = (float*)(ndeg + 100352);          // N (pad 100352)
    __half*       h1u    = (__half*)(dinv + 100352);         // N*16 halves, 3.2 MB
    float2*       h2f    = (float2*)(h1u + (size_t)100352 * H1); // N float2
    unsigned int* eop    = (unsigned int*)(h2f + 100352);    // NB*CAP = 19.9 MB

    hipMemsetAsync(cursor, 0, 16384 * sizeof(int), stream);  // capture-safe

    k_partition<<<PBLK, 512, 0, stream>>>(ei, cursor, eop, x, W1, h1u);
    k_build    <<<NB,   512, 0, stream>>>(cursor, eop, nstart, ndeg, dinv);
    k_agg1     <<<N_NODES / 32, 256, 0, stream>>>(eop, nstart, ndeg, h1u, dinv, b1, W2, h2f);
    k_agg2     <<<N_NODES / 32, 256, 0, stream>>>(eop, nstart, ndeg, h2f, dinv, b2, out);
}

// Round 8
// 210.961 us; speedup vs baseline: 1.6595x; 1.0610x over previous
//
#include <hip/hip_runtime.h>
#include <hip/hip_fp16.h>
#include <math.h>

#define N_NODES 100000
#define N_EDGES 3200000
#define D_IN    128
#define H1      16

#define PSH     8                      // packing shift: (src<<8 | dloc), dloc < 256
#define NPB     200                    // nodes per bucket (non-pow2; magic div)
#define NB      500                    // 500*200 == N exactly
#define CAP     9936                   // region capacity (x16; mean fill ~9264 +5.5sigma)
#define PBLK    512
#define CHUNK   6250                   // N_EDGES / PBLK exact
#define ELS_CAP 13760                  // >= 6250 + 500*15 = 13750, multiple of 16
#define NLINES  (ELS_CAP / 16)         // 860
#define CSTRIDE 32                     // cursor stride in ints: 1 counter per 128B line
#define MROWS   64

// bucket of node d: b = floor(d/200) via magic: (d*671089)>>27  (exact, d<1.86M)
__device__ __forceinline__ unsigned bkt(int d) {
    return (unsigned)(((unsigned long long)(unsigned)d * 671089ull) >> 27);
}

// Pipeline = round-4 split (fusion variants all measured worse: r5 +146, r6 +64,
// r7 +20). eop: NB regions of CAP uints; (src<<8|dloc) runs padded to 16-edge
// 64B lines with 0xFFFFFFFF sentinels, coalesced writeout; build -> compact CSR.
// agg1: 4 lanes/node, 8B gathers (1 eop + 4 gathers per 64 edges per wave).
// agg2: 8 lanes/node, 8B gathers.

// ---- partition: rank -> wave-scan -> LDS bucket-sort -> coalesced writeout ----
__global__ __launch_bounds__(512) void k_partition(const int* __restrict__ ei,
                                                   int* __restrict__ cursor,
                                                   unsigned int* __restrict__ eop) {
    __shared__ int h[512];                       // per-bucket counts (pad to 512)
    __shared__ int loff[512];                    // exclusive local run offsets
    __shared__ int resv[NB];                     // global region offsets
    __shared__ int wsum[8], wpre[8];             // cross-wave scan
    __shared__ unsigned short owner[NLINES];     // line -> bucket
    __shared__ unsigned char rank8[CHUNK];       // per-edge rank in its run (<255)
    __shared__ unsigned int els[ELS_CAP];        // 55 KB staging
    int t = threadIdx.x;
    h[t] = 0;
    __syncthreads();
    int c0 = blockIdx.x * CHUNK;
    const int2* s2 = (const int2*)(ei + c0);
    const int2* d2 = (const int2*)(ei + N_EDGES + c0);
    for (int i = t; i < CHUNK / 2; i += 512) {   // int2 loads: count + rank
        int2 dd = d2[i];
        rank8[2 * i]     = (unsigned char)atomicAdd(&h[bkt(dd.x)], 1);
        rank8[2 * i + 1] = (unsigned char)atomicAdd(&h[bkt(dd.y)], 1);
    }
    __syncthreads();
    int cp = (h[t] + 15) & ~15;                  // run padded to 64B multiple
    int lane = t & 63, w = t >> 6;
    int v = cp;                                  // wave-level inclusive scan
#pragma unroll
    for (int o = 1; o < 64; o <<= 1) {
        int u = __shfl_up(v, o);
        if (lane >= o) v += u;
    }
    if (lane == 63) wsum[w] = v;
    __syncthreads();
    if (t < 8) {
        int s = wsum[t];
#pragma unroll
        for (int o = 1; o < 8; o <<= 1) {
            int u = __shfl_up(s, o);
            if (t >= o) s += u;
        }
        wpre[t] = s;                             // inclusive wave prefix
    }
    __syncthreads();
    int inc = v + ((w > 0) ? wpre[w - 1] : 0);   // inclusive over 512
    int totalpad = wpre[7];                      // <= ELS_CAP by construction
    int ex = inc - cp;                           // exclusive
    loff[t] = ex;
    if (t < NB && cp) {
        resv[t] = atomicAdd(&cursor[t * CSTRIDE], cp);  // 16-aligned
        int l0 = ex >> 4;
        for (int k = 0; k < (cp >> 4); ++k) owner[l0 + k] = (unsigned short)t;
    }
    for (int i = t; i < totalpad; i += 512) els[i] = 0xFFFFFFFFu;   // sentinels
    __syncthreads();
    for (int i = t; i < CHUNK / 2; i += 512) {   // LDS bucket-sort scatter
        int2 ss = s2[i];
        int2 dd = d2[i];                         // L2-hot re-read
        unsigned bx = bkt(dd.x), by = bkt(dd.y);
        els[loff[bx] + (int)rank8[2 * i]] =
            ((unsigned)ss.x << PSH) | (unsigned)(dd.x - (int)(bx * NPB));
        els[loff[by] + (int)rank8[2 * i + 1]] =
            ((unsigned)ss.y << PSH) | (unsigned)(dd.y - (int)(by * NPB));
    }
    __syncthreads();
    for (int i = t; i < totalpad; i += 512) {    // coalesced: full 64B lines
        int b   = owner[i >> 4];
        int pos = resv[b] + (i - loff[b]);
        if (pos < CAP)                           // statistically impossible guard
            eop[(size_t)b * CAP + pos] = els[i];
    }
}

// ---- build: uint4 stage, single count+rank atomic pass, atomic-free compaction ----
__global__ __launch_bounds__(512) void k_build(const int* __restrict__ cursor,
                                               unsigned int* __restrict__ eop,
                                               int* __restrict__ nstart,
                                               int* __restrict__ ndeg,
                                               float* __restrict__ dinv) {
    __shared__ unsigned int els[CAP];   // 39.7 KB
    __shared__ int cnt[256];
    __shared__ int off[256];
    __shared__ int wsum[4], wpre[4];
    int t = threadIdx.x, b = blockIdx.x;
    if (t < 256) cnt[t] = 0;
    __syncthreads();
    int n = cursor[b * CSTRIDE]; if (n > CAP) n = CAP;   // padded fill; mult of 16
    unsigned int* reg = eop + (size_t)b * CAP;
    for (int i4 = t; i4 < (n >> 2); i4 += 512) { // stage + count + rank, one pass
        uint4 wv = ((const uint4*)reg)[i4];
        unsigned int e0 = wv.x, e1 = wv.y, e2 = wv.z, e3 = wv.w;
        int r;
        if ((int)e0 >= 0) { r = atomicAdd(&cnt[e0 & 0xFF], 1); e0 |= (unsigned)r << 25; }
        if ((int)e1 >= 0) { r = atomicAdd(&cnt[e1 & 0xFF], 1); e1 |= (unsigned)r << 25; }
        if ((int)e2 >= 0) { r = atomicAdd(&cnt[e2 & 0xFF], 1); e2 |= (unsigned)r << 25; }
        if ((int)e3 >= 0) { r = atomicAdd(&cnt[e3 & 0xFF], 1); e3 |= (unsigned)r << 25; }
        ((uint4*)els)[i4] = make_uint4(e0, e1, e2, e3);
    }
    __syncthreads();
    int lane = t & 63, w = t >> 6;
    int v = 0;
    if (t < 256) {                               // 4-wave inclusive scan
        v = cnt[t];
#pragma unroll
        for (int o = 1; o < 64; o <<= 1) {
            int u = __shfl_up(v, o);
            if (lane >= o) v += u;
        }
        if (lane == 63) wsum[w] = v;
    }
    __syncthreads();
    if (t < 4) {
        int s = wsum[t];
#pragma unroll
        for (int o = 1; o < 4; o <<= 1) {
            int u = __shfl_up(s, o);
            if (t >= o) s += u;
        }
        wpre[t] = s;
    }
    __syncthreads();
    if (t < 256) {
        int val = cnt[t];
        int ex = (v + ((w > 0) ? wpre[w - 1] : 0)) - val;   // exclusive
        off[t] = ex;
        if (t < NPB) {
            int node = b * NPB + t;              // NB*NPB == N exactly
            nstart[node] = b * CAP + ex;
            ndeg[node]   = val;
            dinv[node]   = rsqrtf((float)(val + 1));   // +1 self-loop
        }
    }
    __syncthreads();
    for (int i4 = t; i4 < (n >> 2); i4 += 512) { // rank-addressed compact CSR
        uint4 wv = ((const uint4*)els)[i4];
        unsigned int e; unsigned s;
        e = wv.x; s = (e >> PSH) & 0x1FFFFu;
        if (s < N_NODES) reg[off[e & 0xFF] + (int)(e >> 25)] = s;
        e = wv.y; s = (e >> PSH) & 0x1FFFFu;
        if (s < N_NODES) reg[off[e & 0xFF] + (int)(e >> 25)] = s;
        e = wv.z; s = (e >> PSH) & 0x1FFFFu;
        if (s < N_NODES) reg[off[e & 0xFF] + (int)(e >> 25)] = s;
        e = wv.w; s = (e >> PSH) & 0x1FFFFu;
        if (s < N_NODES) reg[off[e & 0xFF] + (int)(e >> 25)] = s;
    }
}

// ---- matmul: wave = 64 rows x 4 cols, x in LDS (pad 129), W uniform loads ----
__global__ __launch_bounds__(256) void k_mm1(const float* __restrict__ x,
                                             const float* __restrict__ W1,
                                             const float* __restrict__ dinv,
                                             __half* __restrict__ h1h) {
    __shared__ float sX[MROWS][D_IN + 1];   // 33 KB
    int t = threadIdx.x;
    int r0 = blockIdx.x * MROWS;
    for (int i = t; i < MROWS * (D_IN / 4); i += 256) {
        int row = i >> 5, c4 = i & 31;
        int grow = r0 + row;
        float4 v = (grow < N_NODES) ? ((const float4*)x)[(size_t)grow * 32 + c4]
                                    : make_float4(0.f, 0.f, 0.f, 0.f);
        sX[row][c4 * 4 + 0] = v.x; sX[row][c4 * 4 + 1] = v.y;
        sX[row][c4 * 4 + 2] = v.z; sX[row][c4 * 4 + 3] = v.w;
    }
    __syncthreads();
    int lane = t & 63;
    int c0 = __builtin_amdgcn_readfirstlane((t >> 6) * 4);
    float a0 = 0.f, a1 = 0.f, a2 = 0.f, a3 = 0.f;
#pragma unroll 4
    for (int d = 0; d < D_IN; ++d) {
        float xv = sX[lane][d];
        a0 = fmaf(xv, W1[d * 16 + c0 + 0], a0);
        a1 = fmaf(xv, W1[d * 16 + c0 + 1], a1);
        a2 = fmaf(xv, W1[d * 16 + c0 + 2], a2);
        a3 = fmaf(xv, W1[d * 16 + c0 + 3], a3);
    }
    int grow = r0 + lane;
    if (grow < N_NODES) {
        float di = dinv[grow];
        __half2* o = (__half2*)(h1h + (size_t)grow * H1 + c0);
        o[0] = __floats2half2_rn(a0 * di, a1 * di);
        o[1] = __floats2half2_rn(a2 * di, a3 * di);
    }
}

// ---- layer-1 agg: 4 lanes/node (lane owns 4 of 16 cols), 8B gathers,
//      1 eop load + 4 gathers per 64 edges per wave, dual accumulators ----
__global__ __launch_bounds__(256) void k_agg1(const unsigned int* __restrict__ eop,
                                              const int* __restrict__ nstart,
                                              const int* __restrict__ ndeg,
                                              const __half* __restrict__ h1h,
                                              const float* __restrict__ dinv,
                                              const float* __restrict__ b1,
                                              const float* __restrict__ W2,
                                              float2* __restrict__ h2f) {
    int t = threadIdx.x;
    int g = t >> 2, l = t & 3;               // 64 groups of 4 lanes
    int base = (t & 63) & ~3;                // wave-relative group base lane
    int node = blockIdx.x * 64 + g;
    if (node >= N_NODES) return;             // group-uniform exit
    int e0 = nstart[node], deg = ndeg[node];
    const float2* H = (const float2*)h1h;    // row = 4 float2 (16 halves)
    float a0 = 0.f, a1 = 0.f, a2 = 0.f, a3 = 0.f;   // accum set A (even k)
    float c0 = 0.f, c1 = 0.f, c2 = 0.f, c3 = 0.f;   // accum set B (odd k)
    int nfull = deg & ~3;
    int j = e0;
    for (; j < e0 + nfull; j += 4) {         // 4 edges/group per batch
        int s = (int)eop[j + l];             // coalesced 4-wide per group
#pragma unroll
        for (int k = 0; k < 4; k += 2) {
            int sk0 = __shfl(s, base + k);
            int sk1 = __shfl(s, base + k + 1);
            float2 r0 = H[sk0 * 4 + l];      // 8B gather: lane's 4 cols
            float2 r1 = H[sk1 * 4 + l];
            float2 f00 = __half22float2(*(const __half2*)&r0.x);
            float2 f01 = __half22float2(*(const __half2*)&r0.y);
            float2 f10 = __half22float2(*(const __half2*)&r1.x);
            float2 f11 = __half22float2(*(const __half2*)&r1.y);
            a0 += f00.x; a1 += f00.y; a2 += f01.x; a3 += f01.y;
            c0 += f10.x; c1 += f10.y; c2 += f11.x; c3 += f11.y;
        }
    }
    int r = e0 + deg - j;                    // 0..3 tail
    if (r) {
        int s = (l < r) ? (int)eop[j + l] : -1;
#pragma unroll
        for (int k = 0; k < 4; ++k) {
            int sk = __shfl(s, base + k);
            int su = (sk >= 0) ? sk : 0;
            float m = (sk >= 0) ? 1.f : 0.f;
            float2 rr = H[su * 4 + l];
            float2 f0 = __half22float2(*(const __half2*)&rr.x);
            float2 f1 = __half22float2(*(const __half2*)&rr.y);
            a0 = fmaf(f0.x, m, a0); a1 = fmaf(f0.y, m, a1);
            a2 = fmaf(f1.x, m, a2); a3 = fmaf(f1.y, m, a3);
        }
    }
    float di = dinv[node];
    float2 sr = H[node * 4 + l];             // + self-loop
    float2 s01 = __half22float2(*(const __half2*)&sr.x);
    float2 s23 = __half22float2(*(const __half2*)&sr.y);
    float s0 = (a0 + c0) + s01.x, s1 = (a1 + c1) + s01.y;
    float s2 = (a2 + c2) + s23.x, s3 = (a3 + c3) + s23.y;
    float4 bb = ((const float4*)b1)[l];      // b1[4l .. 4l+3]
    float h0 = fmaxf(fmaf(di, s0, bb.x), 0.f);
    float h1v = fmaxf(fmaf(di, s1, bb.y), 0.f);
    float h2v = fmaxf(fmaf(di, s2, bb.z), 0.f);
    float h3v = fmaxf(fmaf(di, s3, bb.w), 0.f);
    float4 wa = ((const float4*)W2)[2 * l];      // W2 rows 4l, 4l+1
    float4 wb = ((const float4*)W2)[2 * l + 1];  // W2 rows 4l+2, 4l+3
    float p0 = h0 * wa.x + h1v * wa.z + h2v * wb.x + h3v * wb.z;
    float p1 = h0 * wa.y + h1v * wa.w + h2v * wb.y + h3v * wb.w;
    p0 += __shfl_xor(p0, 1); p1 += __shfl_xor(p1, 1);
    p0 += __shfl_xor(p0, 2); p1 += __shfl_xor(p1, 2);
    if (l == 0) h2f[node] = make_float2(p0 * di, p1 * di);
}

// ---- layer-2 agg: 8 lanes/node + b2 + log_softmax ----
__global__ __launch_bounds__(256) void k_agg2(const unsigned int* __restrict__ eop,
                                              const int* __restrict__ nstart,
                                              const int* __restrict__ ndeg,
                                              const float2* __restrict__ h2f,
                                              const float* __restrict__ dinv,
                                              const float* __restrict__ b2,
                                              float* __restrict__ out) {
    int tg = blockIdx.x * 256 + threadIdx.x;
    int node = tg >> 3, l = tg & 7;          // 3125*256/8 == N exactly
    int e0 = nstart[node], e1 = e0 + ndeg[node];
    float ax = 0.f, ay = 0.f;
    for (int j = e0 + l; j < e1; j += 8) {
        float2 m = h2f[eop[j]];
        ax += m.x; ay += m.y;
    }
    ax += __shfl_xor(ax, 1); ay += __shfl_xor(ay, 1);
    ax += __shfl_xor(ax, 2); ay += __shfl_xor(ay, 2);
    ax += __shfl_xor(ax, 4); ay += __shfl_xor(ay, 4);
    if (l == 0) {
        float di = dinv[node];
        float2 self = h2f[node];
        float a0 = fmaf(di, ax + self.x, b2[0]);
        float a1 = fmaf(di, ay + self.y, b2[1]);
        float m  = fmaxf(a0, a1);
        float lg = logf(expf(a0 - m) + expf(a1 - m));
        out[2 * node]     = a0 - m - lg;
        out[2 * node + 1] = a1 - m - lg;
    }
}

extern "C" void kernel_launch(void* const* d_in, const int* in_sizes, int n_in,
                              void* d_out, int out_size, void* d_ws, size_t ws_size,
                              hipStream_t stream) {
    const float* x  = (const float*)d_in[0];
    const int*   ei = (const int*)d_in[1];
    const float* W1 = (const float*)d_in[2];
    const float* b1 = (const float*)d_in[3];
    const float* W2 = (const float*)d_in[4];
    const float* b2 = (const float*)d_in[5];
    float* out = (float*)d_out;

    // workspace carve (~25.2 MB); eop base offset 5283840 B = 64B-aligned
    int*          cursor = (int*)d_ws;                       // 500 ctrs, stride 32 ints
    int*          nstart = cursor + 16384;                   // N (pad 100352)
    int*          ndeg   = nstart + 100352;                  // N (pad 100352)
    float*        dinv   = (float*)(ndeg + 100352);          // N (pad 100352)
    __half*       h1h    = (__half*)(dinv + 100352);         // N*16 halves, 3.2 MB
    float2*       h2f    = (float2*)(h1h + (size_t)100352 * H1); // N float2
    unsigned int* eop    = (unsigned int*)(h2f + 100352);    // NB*CAP = 19.9 MB

    hipMemsetAsync(cursor, 0, 16384 * sizeof(int), stream);  // capture-safe

    k_partition<<<PBLK, 512, 0, stream>>>(ei, cursor, eop);
    k_build    <<<NB,   512, 0, stream>>>(cursor, eop, nstart, ndeg, dinv);
    k_mm1      <<<(N_NODES + MROWS - 1) / MROWS, 256, 0, stream>>>(x, W1, dinv, h1h);
    k_agg1     <<<(N_NODES + 63) / 64, 256, 0, stream>>>(eop, nstart, ndeg, h1h, dinv, b1, W2, h2f);
    k_agg2     <<<N_NODES / 32, 256, 0, stream>>>(eop, nstart, ndeg, h2f, dinv, b2, out);
}